// Round 5
// baseline (523.176 us; speedup 1.0000x reference)
//
#include <hip/hip_runtime.h>
#include <hip/hip_bf16.h>

// SVXSoftmax: cos = norm(input) @ norm(weight)^T ; margin transform ; *32
// B=512, D=512, C=100000.  out[512][100000] f32.
//
// r5: persistent-block pipelined GEMM.
//  - prep packs bf16-normalized input (fragment-order, L2-resident, 512KB).
//  - gemm: 256 persistent blocks (1/CU, LDS-capped), each handles ~6 column
//    tiles of 64 classes. Double-buffered 64KB LDS B-tiles (raw bf16 W,
//    invnorm applied post-MFMA). Per round: issue next tile's W f32 loads
//    (T14 issue-early) -> K-loop (16 steps, distance-3 A prefetch from L2)
//    -> sumsq+convert+ds_write next buffer -> fused margin epilogue -> one
//    barrier. __launch_bounds__(512,2) => 256-VGPR cap (r4 spilled at 128).
//  - plain stores (NT stores = +43% write amplification, r3).

#define S_SCALE 32.0f
#define MARGIN  0.35f
#define T_BOOST 0.2f
#define EPSN    1e-12f

constexpr int Bn = 512;      // batch
constexpr int Dn = 512;      // dim
constexpr int Cn = 100000;   // classes
constexpr int BN = 64;       // classes per tile
constexpr int NT = (Cn + BN - 1) / BN;   // 1563 tiles
constexpr int GRID = 256;    // persistent blocks (1 per CU)

typedef __attribute__((ext_vector_type(8))) short bf16x8;
typedef __attribute__((ext_vector_type(4))) float f32x4;

static __device__ inline unsigned short f32_bf16(float f) {
    unsigned int u = __float_as_uint(f);
    u += 0x7FFFu + ((u >> 16) & 1u);     // round-to-nearest-even
    return (unsigned short)(u >> 16);
}

// packed A layout: byte = (g<<14) + (s<<10) + (lane<<4) + j*2
//   g = row>>4, s = col>>5, lane = ((col>>3)&3)*16 + (row&15), j = col&7
__global__ __launch_bounds__(256) void prep_kernel(const float* __restrict__ in,
                                                   const float* __restrict__ w,
                                                   const int* __restrict__ label,
                                                   float* __restrict__ gt,
                                                   unsigned short* __restrict__ in_p) {
    int b = blockIdx.x, t = threadIdx.x;
    const float* irow = in + (size_t)b * Dn;
    int lab = label[b];
    const float* wrow = w + (size_t)lab * Dn;
    int c = 2 * t;
    float xa = irow[c], xb = irow[c + 1];
    float ya = wrow[c], yb = wrow[c + 1];
    float s_ii = xa*xa + xb*xb, s_ww = ya*ya + yb*yb, s_iw = xa*ya + xb*yb;
    #pragma unroll
    for (int off = 32; off; off >>= 1) {
        s_ii += __shfl_xor(s_ii, off);
        s_ww += __shfl_xor(s_ww, off);
        s_iw += __shfl_xor(s_iw, off);
    }
    __shared__ float r0[4], r1[4], r2[4], bc[1];
    int wid = t >> 6;
    if ((t & 63) == 0) { r0[wid] = s_ii; r1[wid] = s_ww; r2[wid] = s_iw; }
    __syncthreads();
    if (t == 0) {
        float a  = r0[0] + r0[1] + r0[2] + r0[3];
        float cc = r1[0] + r1[1] + r1[2] + r1[3];
        float d  = r2[0] + r2[1] + r2[2] + r2[3];
        float inv_i = 1.0f / fmaxf(sqrtf(a), EPSN);
        float g = d * inv_i / fmaxf(sqrtf(cc), EPSN);
        gt[b] = fminf(fmaxf(g, -1.0f), 1.0f);
        bc[0] = inv_i;
    }
    __syncthreads();
    float inv_i = bc[0];
    int g = b >> 4, l15 = b & 15;
    int s = t >> 4, lk = (t >> 2) & 3, j2 = (t & 3) * 4;
    int lane = lk * 16 + l15;
    unsigned int off = (unsigned)((g << 14) + (s << 10) + (lane << 4)) + j2;
    unsigned int h0 = f32_bf16(xa * inv_i), h1 = f32_bf16(xb * inv_i);
    *(unsigned int*)((char*)in_p + off) = h0 | (h1 << 16);
}

// ---------------- persistent fused GEMM + margin ----------------
__global__ __launch_bounds__(512, 2) void gemm_kernel(const unsigned short* __restrict__ in_p,
                                                      const float* __restrict__ w,
                                                      const float* __restrict__ gt,
                                                      const int* __restrict__ label,
                                                      float* __restrict__ out) {
    __shared__ unsigned short Bs[2][BN * 512];   // 2 x 64 KB, raw bf16 W
    __shared__ float inv_s[2][BN];

    int t = threadIdx.x, wid = t >> 6, lane = t & 63;
    int l15 = lane & 15, lk = lane >> 4;
    int rl = t >> 3, kc = t & 7;                 // staging: 64 rows x 8 lanes

    int bid = blockIdx.x;
    int my_nt = NT / GRID + (bid < (NT - (NT / GRID) * GRID) ? 1 : 0);  // 6 or 7

    const char* apb = (const char*)in_p + ((wid * 4) << 14) + (lane << 4);

    f32x4 wv[16];

    // ---- prologue: stage tile(bid) into buf 0 ----
    {
        int rg = bid * BN + rl; if (rg >= Cn) rg = Cn - 1;
        const float* wr = w + (size_t)rg * Dn + kc * 8;
        #pragma unroll
        for (int i = 0; i < 8; ++i) {
            wv[2*i]   = *(const f32x4*)(wr + i * 64);
            wv[2*i+1] = *(const f32x4*)(wr + i * 64 + 4);
        }
        float ss = 0.f;
        #pragma unroll
        for (int i = 0; i < 16; ++i)
            ss += wv[i][0]*wv[i][0] + wv[i][1]*wv[i][1] + wv[i][2]*wv[i][2] + wv[i][3]*wv[i][3];
        ss += __shfl_xor(ss, 1); ss += __shfl_xor(ss, 2); ss += __shfl_xor(ss, 4);
        char* nb = (char*)&Bs[0][0];
        #pragma unroll
        for (int i = 0; i < 8; ++i) {
            bf16x8 hv;
            #pragma unroll
            for (int j = 0; j < 4; ++j) {
                hv[j]     = (short)f32_bf16(wv[2*i][j]);
                hv[4 + j] = (short)f32_bf16(wv[2*i+1][j]);
            }
            unsigned int off = (unsigned)(((rl << 10) + (kc << 4) + (i << 7)) ^ ((rl & 7) << 4));
            *(bf16x8*)(nb + off) = hv;
        }
        if (kc == 0) inv_s[0][rl] = 1.0f / fmaxf(sqrtf(ss), EPSN);
    }
    __syncthreads();

    for (int r = 0; r < my_nt; ++r) {
        int cur = r & 1;
        int tile = bid + r * GRID;
        bool stage = (r + 1 < my_nt);

        // ---- issue next tile's W loads early (latency hides under K-loop) ----
        if (stage) {
            int rg = (tile + GRID) * BN + rl; if (rg >= Cn) rg = Cn - 1;
            const float* wr = w + (size_t)rg * Dn + kc * 8;
            #pragma unroll
            for (int i = 0; i < 8; ++i) {
                wv[2*i]   = *(const f32x4*)(wr + i * 64);
                wv[2*i+1] = *(const f32x4*)(wr + i * 64 + 4);
            }
        }

        // ---- K-loop on buf[cur]: 16 steps, distance-3 A prefetch ----
        const char* bsb = (const char*)&Bs[cur][0];
        f32x4 acc[4][4];
        #pragma unroll
        for (int m = 0; m < 4; ++m)
            #pragma unroll
            for (int n = 0; n < 4; ++n) acc[m][n] = (f32x4){0.f, 0.f, 0.f, 0.f};

        bf16x8 ar[3][4];
        #pragma unroll
        for (int s = 0; s < 3; ++s)
            #pragma unroll
            for (int m = 0; m < 4; ++m)
                ar[s][m] = *(const bf16x8*)(apb + (m << 14) + (s << 10));

        #pragma unroll
        for (int s = 0; s < 16; ++s) {
            bf16x8 bfrag[4];
            #pragma unroll
            for (int nf = 0; nf < 4; ++nf) {
                int br = nf * 16 + l15;
                bfrag[nf] = *(const bf16x8*)(bsb + ((((br << 10) + (s << 6) + (lk << 4))) ^ ((br & 7) << 4)));
            }
            #pragma unroll
            for (int m = 0; m < 4; ++m)
                #pragma unroll
                for (int nf = 0; nf < 4; ++nf)
                    acc[m][nf] = __builtin_amdgcn_mfma_f32_16x16x32_bf16(ar[s % 3][m], bfrag[nf], acc[m][nf], 0, 0, 0);
            if (s + 3 < 16) {
                #pragma unroll
                for (int m = 0; m < 4; ++m)
                    ar[s % 3][m] = *(const bf16x8*)(apb + (m << 14) + ((s + 3) << 10));
            }
        }

        // ---- finish staging next tile: sumsq, convert, ds_write buf[cur^1] ----
        if (stage) {
            float ss = 0.f;
            #pragma unroll
            for (int i = 0; i < 16; ++i)
                ss += wv[i][0]*wv[i][0] + wv[i][1]*wv[i][1] + wv[i][2]*wv[i][2] + wv[i][3]*wv[i][3];
            ss += __shfl_xor(ss, 1); ss += __shfl_xor(ss, 2); ss += __shfl_xor(ss, 4);
            char* nb = (char*)&Bs[cur ^ 1][0];
            #pragma unroll
            for (int i = 0; i < 8; ++i) {
                bf16x8 hv;
                #pragma unroll
                for (int j = 0; j < 4; ++j) {
                    hv[j]     = (short)f32_bf16(wv[2*i][j]);
                    hv[4 + j] = (short)f32_bf16(wv[2*i+1][j]);
                }
                unsigned int off = (unsigned)(((rl << 10) + (kc << 4) + (i << 7)) ^ ((rl & 7) << 4));
                *(bf16x8*)(nb + off) = hv;
            }
            if (kc == 0) inv_s[cur ^ 1][rl] = 1.0f / fmaxf(sqrtf(ss), EPSN);
        }

        // ---- fused epilogue for tile (invnorm post-MFMA) ----
        float invc[4];
        #pragma unroll
        for (int nf = 0; nf < 4; ++nf) invc[nf] = inv_s[cur][nf * 16 + l15];
        int cb = tile * BN;
        #pragma unroll
        for (int m = 0; m < 4; ++m) {
            #pragma unroll
            for (int r4 = 0; r4 < 4; ++r4) {
                int b_row = wid * 64 + m * 16 + lk * 4 + r4;
                float thr = gt[b_row] - MARGIN;
                int lab   = label[b_row];
                float gv  = thr * S_SCALE;
                size_t obase = (size_t)b_row * Cn;
                #pragma unroll
                for (int nf = 0; nf < 4; ++nf) {
                    int c = cb + nf * 16 + l15;
                    if (c < Cn) {
                        float cosv = acc[m][nf][r4] * invc[nf];
                        cosv = fminf(fmaxf(cosv, -1.0f), 1.0f);
                        float o = (cosv > thr) ? ((T_BOOST + 1.0f) * cosv + T_BOOST) : cosv;
                        o *= S_SCALE;
                        if (c == lab) o = gv;
                        out[obase + c] = o;
                    }
                }
            }
        }
        __syncthreads();
    }
}

extern "C" void kernel_launch(void* const* d_in, const int* in_sizes, int n_in,
                              void* d_out, int out_size, void* d_ws, size_t ws_size,
                              hipStream_t stream) {
    const float* in  = (const float*)d_in[0];
    const float* w   = (const float*)d_in[1];
    const int* label = (const int*)d_in[2];
    float* out = (float*)d_out;

    char* ws = (char*)d_ws;
    float* gt            = (float*)ws;                   // 512 f32
    unsigned short* in_p = (unsigned short*)(ws + 4096); // packed 512KB

    prep_kernel<<<dim3(Bn), dim3(256), 0, stream>>>(in, w, label, gt, in_p);
    gemm_kernel<<<dim3(GRID), dim3(512), 0, stream>>>(in_p, w, gt, label, out);
}

// Round 6
// 191.724 us; speedup vs baseline: 2.7288x; 2.7288x over previous
//
#include <hip/hip_runtime.h>
#include <hip/hip_bf16.h>

// SVXSoftmax: cos = norm(input) @ norm(weight)^T ; margin transform ; *32
// B=512, D=512, C=100000.  out[512][100000] f32.
//
// r6 = r1 base (165us, VGPR56, no spill, FETCH=205MB exact) + three fixes:
//  - per-K-step double-buffered B staging, issue-early (one barrier/step,
//    B-load latency hides under current step's ds_read+MFMA)
//  - packed-A fragment layout in L2 (r3), dist-2 prefetch, FULL unroll so
//    every register index is static (r4/r5 died to spills from long-lived
//    register staging; here staged B lives ONE step = 8 regs)
//  - raw bf16 B in LDS, invnorm applied post-MFMA; sumsq accumulated
//    incrementally by staging threads (no second W pass)

#define S_SCALE 32.0f
#define MARGIN  0.35f
#define T_BOOST 0.2f
#define EPSN    1e-12f

constexpr int Bn = 512;      // batch
constexpr int Dn = 512;      // dim
constexpr int Cn = 100000;   // classes
constexpr int BM = 256, BN = 128, BK = 32;
constexpr int PAD = 40;      // bf16 elems per LDS row (80B stride, r1-proven)

typedef __attribute__((ext_vector_type(8))) short bf16x8;
typedef __attribute__((ext_vector_type(4))) float f32x4;

static __device__ inline unsigned short f32_bf16(float f) {
    unsigned int u = __float_as_uint(f);
    u += 0x7FFFu + ((u >> 16) & 1u);     // round-to-nearest-even
    return (unsigned short)(u >> 16);
}

// packed A layout: byte = (g<<14) + (s<<10) + (lane<<4) + j*2
//   g = row>>4, s = col>>5, lane = ((col>>3)&3)*16 + (row&15), j = col&7
__global__ __launch_bounds__(256) void prep_kernel(const float* __restrict__ in,
                                                   const float* __restrict__ w,
                                                   const int* __restrict__ label,
                                                   float* __restrict__ gt,
                                                   unsigned short* __restrict__ in_p) {
    int b = blockIdx.x, t = threadIdx.x;
    const float* irow = in + (size_t)b * Dn;
    int lab = label[b];
    const float* wrow = w + (size_t)lab * Dn;
    int c = 2 * t;
    float xa = irow[c], xb = irow[c + 1];
    float ya = wrow[c], yb = wrow[c + 1];
    float s_ii = xa*xa + xb*xb, s_ww = ya*ya + yb*yb, s_iw = xa*ya + xb*yb;
    #pragma unroll
    for (int off = 32; off; off >>= 1) {
        s_ii += __shfl_xor(s_ii, off);
        s_ww += __shfl_xor(s_ww, off);
        s_iw += __shfl_xor(s_iw, off);
    }
    __shared__ float r0[4], r1[4], r2[4], bc[1];
    int wid = t >> 6;
    if ((t & 63) == 0) { r0[wid] = s_ii; r1[wid] = s_ww; r2[wid] = s_iw; }
    __syncthreads();
    if (t == 0) {
        float a  = r0[0] + r0[1] + r0[2] + r0[3];
        float cc = r1[0] + r1[1] + r1[2] + r1[3];
        float d  = r2[0] + r2[1] + r2[2] + r2[3];
        float inv_i = 1.0f / fmaxf(sqrtf(a), EPSN);
        float g = d * inv_i / fmaxf(sqrtf(cc), EPSN);
        gt[b] = fminf(fmaxf(g, -1.0f), 1.0f);
        bc[0] = inv_i;
    }
    __syncthreads();
    float inv_i = bc[0];
    int g = b >> 4, l15 = b & 15;
    int s = t >> 4, lk = (t >> 2) & 3, j2 = (t & 3) * 4;
    int lane = lk * 16 + l15;
    unsigned int off = (unsigned)((g << 14) + (s << 10) + (lane << 4)) + j2;
    unsigned int h0 = f32_bf16(xa * inv_i), h1 = f32_bf16(xb * inv_i);
    *(unsigned int*)((char*)in_p + off) = h0 | (h1 << 16);
}

// ---------------- fused convert+GEMM+margin ----------------
__global__ __launch_bounds__(512) void gemm_kernel(const unsigned short* __restrict__ in_p,
                                                   const float* __restrict__ w,
                                                   const float* __restrict__ gt,
                                                   const int* __restrict__ label,
                                                   float* __restrict__ out) {
    __shared__ unsigned short Bs[2][BN * PAD];   // 2 x 10240 B, raw bf16 W
    __shared__ float inv_s[BN];

    int t = threadIdx.x, wid = t >> 6, lane = t & 63;
    int wm = wid >> 1, wn = wid & 1;             // 4x2 waves, wave = 64M x 64N
    int l15 = lane & 15, lk = lane >> 4;
    int bm = blockIdx.x, bn = blockIdx.y;

    // staging map: thread t -> local row t>>2 (0..127), 16B chunk q = t&3
    int srow = t >> 2, q = t & 3;
    int rg = bn * BN + srow; if (rg >= Cn) rg = Cn - 1;
    const float* wsrc = w + (size_t)rg * Dn + q * 8;
    char* sdst0 = (char*)&Bs[0][0] + srow * (PAD * 2) + q * 16;
    char* sdst1 = (char*)&Bs[1][0] + srow * (PAD * 2) + q * 16;

    const char* apb = (const char*)in_p + (((bm * 16 + wm * 4)) << 14) + (lane << 4);

    float ss = 0.f;                               // partial sumsq (this thread's chunks)
    f32x4 acc[4][4];
    #pragma unroll
    for (int m = 0; m < 4; ++m)
        #pragma unroll
        for (int n = 0; n < 4; ++n) acc[m][n] = (f32x4){0.f, 0.f, 0.f, 0.f};

    // ---- prologue: stage step 0 into buf0 ----
    {
        f32x4 b0 = *(const f32x4*)(wsrc);
        f32x4 b1 = *(const f32x4*)(wsrc + 4);
        ss += b0[0]*b0[0] + b0[1]*b0[1] + b0[2]*b0[2] + b0[3]*b0[3]
            + b1[0]*b1[0] + b1[1]*b1[1] + b1[2]*b1[2] + b1[3]*b1[3];
        bf16x8 hv;
        #pragma unroll
        for (int j = 0; j < 4; ++j) { hv[j] = (short)f32_bf16(b0[j]); hv[4+j] = (short)f32_bf16(b1[j]); }
        *(bf16x8*)sdst0 = hv;
    }
    // A prefetch: steps 0,1
    bf16x8 ar[2][4];
    #pragma unroll
    for (int s = 0; s < 2; ++s)
        #pragma unroll
        for (int m = 0; m < 4; ++m)
            ar[s][m] = *(const bf16x8*)(apb + (m << 14) + (s << 10));
    __syncthreads();

    // ---- main loop: 16 K-steps, fully unrolled (static reg indices) ----
    #pragma unroll
    for (int kt = 0; kt < 16; ++kt) {
        // issue next step's B loads (consumed at bottom of this step)
        f32x4 b0, b1;
        if (kt < 15) {
            b0 = *(const f32x4*)(wsrc + (kt + 1) * BK);
            b1 = *(const f32x4*)(wsrc + (kt + 1) * BK + 4);
        }
        // current step's B fragments from LDS
        const char* bsb = (const char*)&Bs[kt & 1][0];
        bf16x8 bfrag[4];
        #pragma unroll
        for (int nf = 0; nf < 4; ++nf) {
            int br = wn * 64 + nf * 16 + l15;
            bfrag[nf] = *(const bf16x8*)(bsb + br * (PAD * 2) + lk * 16);
        }
        #pragma unroll
        for (int m = 0; m < 4; ++m)
            #pragma unroll
            for (int nf = 0; nf < 4; ++nf)
                acc[m][nf] = __builtin_amdgcn_mfma_f32_16x16x32_bf16(ar[kt & 1][m], bfrag[nf], acc[m][nf], 0, 0, 0);
        // refill A slot with step kt+2
        if (kt + 2 < 16) {
            #pragma unroll
            for (int m = 0; m < 4; ++m)
                ar[kt & 1][m] = *(const bf16x8*)(apb + (m << 14) + ((kt + 2) << 10));
        }
        // convert + write next step's B into the other buffer
        if (kt < 15) {
            ss += b0[0]*b0[0] + b0[1]*b0[1] + b0[2]*b0[2] + b0[3]*b0[3]
                + b1[0]*b1[0] + b1[1]*b1[1] + b1[2]*b1[2] + b1[3]*b1[3];
            bf16x8 hv;
            #pragma unroll
            for (int j = 0; j < 4; ++j) { hv[j] = (short)f32_bf16(b0[j]); hv[4+j] = (short)f32_bf16(b1[j]); }
            *(bf16x8*)(((kt & 1) ? sdst0 : sdst1)) = hv;
        }
        __syncthreads();
    }

    // ---- invnorm: reduce sumsq across the 4 chunk-threads per row ----
    ss += __shfl_xor(ss, 1); ss += __shfl_xor(ss, 2);
    if (q == 0) inv_s[srow] = 1.0f / fmaxf(sqrtf(ss), EPSN);
    __syncthreads();

    float invc[4];
    #pragma unroll
    for (int nf = 0; nf < 4; ++nf) invc[nf] = inv_s[wn * 64 + nf * 16 + l15];

    // ---- epilogue: invnorm, clamp, margin, label scatter, scale ----
    #pragma unroll
    for (int m = 0; m < 4; ++m) {
        #pragma unroll
        for (int r = 0; r < 4; ++r) {
            int b_row = bm * BM + wm * 64 + m * 16 + lk * 4 + r;
            float thr = gt[b_row] - MARGIN;
            int lab   = label[b_row];
            float gv  = thr * S_SCALE;
            size_t obase = (size_t)b_row * Cn;
            #pragma unroll
            for (int nf = 0; nf < 4; ++nf) {
                int c = bn * BN + wn * 64 + nf * 16 + l15;
                if (c < Cn) {
                    float cosv = acc[m][nf][r] * invc[nf];
                    cosv = fminf(fmaxf(cosv, -1.0f), 1.0f);
                    float o = (cosv > thr) ? ((T_BOOST + 1.0f) * cosv + T_BOOST) : cosv;
                    o *= S_SCALE;
                    if (c == lab) o = gv;
                    out[obase + c] = o;
                }
            }
        }
    }
}

extern "C" void kernel_launch(void* const* d_in, const int* in_sizes, int n_in,
                              void* d_out, int out_size, void* d_ws, size_t ws_size,
                              hipStream_t stream) {
    const float* in  = (const float*)d_in[0];
    const float* w   = (const float*)d_in[1];
    const int* label = (const int*)d_in[2];
    float* out = (float*)d_out;

    char* ws = (char*)d_ws;
    float* gt            = (float*)ws;                   // 512 f32
    unsigned short* in_p = (unsigned short*)(ws + 4096); // packed 512KB

    prep_kernel<<<dim3(Bn), dim3(256), 0, stream>>>(in, w, label, gt, in_p);
    dim3 grid(2, (Cn + BN - 1) / BN);   // M fast -> M-pair shares W via L2/L3
    gemm_kernel<<<grid, dim3(512), 0, stream>>>(in_p, w, gt, label, out);
}